// Round 9
// baseline (1912.112 us; speedup 1.0000x reference)
//
#include <hip/hip_runtime.h>

#define SCALE_LORA 2.0f
// GEMM: 128x256 tile, BK=32, 8 waves (2M x 4N, 64x64 each), 32x32x16 MFMA,
// NBUF=3 (72 KiB LDS), 2 blocks/CU, fixed swizzle ((row>>1)&3), XCD panel map.
#define BM 128
#define BN 256
#define BK 32

#define AS1 __attribute__((address_space(1)))
#define AS3 __attribute__((address_space(3)))

using bf16x8 = __attribute__((ext_vector_type(8))) __bf16;
using f32x4  = __attribute__((ext_vector_type(4))) float;
using f32x16 = __attribute__((ext_vector_type(16))) float;
using u16x8  = __attribute__((ext_vector_type(8))) unsigned short;

#define MFMA32(a, b, c) __builtin_amdgcn_mfma_f32_32x32x16_bf16((a), (b), (c), 0, 0, 0)

static __device__ __forceinline__ unsigned short f2bf_rne(float f) {
  unsigned int u = __builtin_bit_cast(unsigned int, f);
  u += 0x7FFFu + ((u >> 16) & 1u);   // round-to-nearest-even
  return (unsigned short)(u >> 16);
}

// ---------- kernel 1: x f32 -> bf16 (vectorized, grid-stride) ----------
__global__ void cvt_bf16_kernel(const float* __restrict__ x,
                                unsigned short* __restrict__ xb, long n) {
  long stride = (long)gridDim.x * blockDim.x;
  long nv = n >> 3;
  for (long i = (long)blockIdx.x * blockDim.x + threadIdx.x; i < nv; i += stride) {
    long base = i << 3;
    f32x4 a = *(const f32x4*)(x + base);
    f32x4 b = *(const f32x4*)(x + base + 4);
    u16x8 o;
    o[0] = f2bf_rne(a[0]); o[1] = f2bf_rne(a[1]);
    o[2] = f2bf_rne(a[2]); o[3] = f2bf_rne(a[3]);
    o[4] = f2bf_rne(b[0]); o[5] = f2bf_rne(b[1]);
    o[6] = f2bf_rne(b[2]); o[7] = f2bf_rne(b[3]);
    *(u16x8*)(xb + base) = o;
  }
}

// ---------- kernel 2: W_eff^T = (W + 2*A@B)^T as bf16, N x K ----------
__global__ void build_wt_kernel(const float* __restrict__ W,
                                const float* __restrict__ A,
                                const float* __restrict__ Bmat,
                                unsigned short* __restrict__ WT,
                                int K, int N, int R) {
  __shared__ float Bs[16][64];
  __shared__ unsigned short Tt[64][66];
  int ntn = N >> 6;
  int kt = blockIdx.x / ntn, nt = blockIdx.x - kt * ntn;
  int k0 = kt << 6, n0 = nt << 6;
  int t = threadIdx.x;
  int tx = t & 63, ty = t >> 6;

  for (int i = t; i < R * 64; i += 256)
    Bs[i >> 6][i & 63] = Bmat[(long)(i >> 6) * N + n0 + (i & 63)];
  __syncthreads();

  for (int it = 0; it < 16; ++it) {
    int kl = (it << 2) + ty;
    long kg = k0 + kl;
    float w = W[kg * N + n0 + tx];
    const float* Ar = A + kg * R;
    float s = 0.f;
    for (int r = 0; r < R; ++r) s += Ar[r] * Bs[r][tx];
    Tt[kl][tx] = f2bf_rne(w + SCALE_LORA * s);
  }
  __syncthreads();

  for (int it = 0; it < 16; ++it) {
    int nn = (it << 2) + ty;
    WT[(long)(n0 + nn) * K + k0 + tx] = Tt[tx][nn];
  }
}

// ---------- kernel 3: 2-blocks/CU 32x32-MFMA GEMM, ring-3 ----------
// 64-B rows (BK=32): effective bank-slot = (row&1)*4 + granule. Swizzle:
// stored granule = logical ^ ((row>>1)&3) -> within each 16-lane phase the
// 8 slots get exactly 2 lanes (free). Applied as inverse-swizzled GLOBAL
// SOURCE (linear gload_lds dest) + swizzled ds_read addr (involution).
__global__ __launch_bounds__(512, 4) void gemm_kernel(
    const unsigned short* __restrict__ Xb,  // M x K bf16
    const unsigned short* __restrict__ WT,  // N x K bf16 (pre-transposed)
    const float* __restrict__ bias,         // N f32
    float* __restrict__ out,                // M x N f32
    int M, int N, int K)
{
  extern __shared__ unsigned short lds[];   // 72 KiB
  // A: 3 bufs x 8192 B at b*8192; B: 3 bufs x 16384 B at 24576 + b*16384.

  int ntm = M / BM, ntn = N / BN;
  int bid = blockIdx.x;
  int tm, tn;
  if (ntn == 16 && (ntm & 7) == 0 && ((gridDim.x & 7) == 0)) {
    // XCD panel map: xcd = bid&7 (hardware round-robin). Each XCD walks one
    // A-panel (L2-resident) across all 16 B-panels (L3-resident); A is
    // fetched from HBM exactly once device-wide. Bijective.
    int xcd = bid & 7, slot = bid >> 3;
    tm = ((slot >> 4) << 3) + xcd;
    tn = slot & 15;
  } else {
    tm = bid / ntn; tn = bid - tm * ntn;
  }
  const long m0 = (long)tm * BM;
  const long n0 = (long)tn * BN;

  int tid  = threadIdx.x;
  int lane = tid & 63;
  int wave = tid >> 6;
  int wr = wave >> 2;        // 0..1 : 64-row half (M)
  int wc = wave & 3;         // 0..3 : 64-col quarter (N)
  int l31 = lane & 31;
  int g   = lane >> 5;       // 0..1 (k-granule within K=16 MFMA fragment)

  f32x16 acc[2][2] = {};     // [fm][fn], 64 f32/lane (AGPR)

  // staging: thread t -> row t>>2, dest granule t&3; source granule =
  // (t&3) ^ ((row>>1)&3) = (t&3) ^ ((t>>3)&3)   [B's +128 rows: 128>>1≡0 mod 4]
  int srccol = 8 * ((tid & 3) ^ ((tid >> 3) & 3));
  const unsigned short* aSrc = Xb + (m0 + (tid >> 2)) * (long)K + srccol;
  const unsigned short* bSrc = WT + (n0 + (tid >> 2)) * (long)K + srccol;
  const int ldsByte = tid * 16;

  // fragment reads: logical granule = 2*ks + g; stored slot ^= (row>>1)&3.
  // wr*64, +32 offsets are ≡0 mod 4 after >>1, so (row>>1)&3 = (l31>>1)&3.
  const int rsw   = (l31 >> 1) & 3;
  const int slot0 = 16 * ((g) ^ rsw);        // ks=0
  const int slot1 = 16 * ((2 + g) ^ rsw);    // ks=1
  const int rowA0 = (wr * 64 + l31) * 64;
  const int rowA1 = (wr * 64 + 32 + l31) * 64;
  const int rowB0 = (wc * 64 + l31) * 64;
  const int rowB1 = (wc * 64 + 32 + l31) * 64;

  const int nt = K / BK;     // 128

  // stage tile kt into buf: A = 1 load, B = 2 loads (3 total)
#define STAGE(buf, kt) do {                                                  \
    __builtin_amdgcn_global_load_lds(                                        \
      (const AS1 void*)(aSrc + (long)(kt) * BK),                             \
      (AS3 void*)((char*)lds + (buf)*8192 + ldsByte), 16, 0, 0);             \
    _Pragma("unroll")                                                        \
    for (int j_ = 0; j_ < 2; ++j_)                                           \
      __builtin_amdgcn_global_load_lds(                                      \
        (const AS1 void*)(bSrc + j_*128*(long)K + (long)(kt) * BK),          \
        (AS3 void*)((char*)lds + 24576 + (buf)*16384 + j_*8192 + ldsByte),   \
        16, 0, 0);                                                           \
  } while (0)

#define SBAR  __builtin_amdgcn_sched_barrier(0)
#define BAR   __builtin_amdgcn_s_barrier()

  // One K-tile: top vmcnt+BAR (per-wave drain + rendezvous); 8 ds_reads;
  // MFMA ks0 (compiler emits counted lgkm — slot1 reads fly under it);
  // lgkm0+BAR rendezvous closes all reads of this buf; stage tile u+3 into
  // the just-freed buf; MFMA ks1.
#define TILE(BUFI, VMSTR, STG) do {                                          \
    asm volatile("s_waitcnt vmcnt(" VMSTR ")" ::: "memory");                 \
    BAR;                                                                     \
    const char* Ab_ = (const char*)lds + (BUFI)*8192;                        \
    const char* Bb_ = (const char*)lds + 24576 + (BUFI)*16384;               \
    bf16x8 a00 = *(const bf16x8*)(Ab_ + rowA0 + slot0);                      \
    bf16x8 a10 = *(const bf16x8*)(Ab_ + rowA1 + slot0);                      \
    bf16x8 b00 = *(const bf16x8*)(Bb_ + rowB0 + slot0);                      \
    bf16x8 b10 = *(const bf16x8*)(Bb_ + rowB1 + slot0);                      \
    bf16x8 a01 = *(const bf16x8*)(Ab_ + rowA0 + slot1);                      \
    bf16x8 a11 = *(const bf16x8*)(Ab_ + rowA1 + slot1);                      \
    bf16x8 b01 = *(const bf16x8*)(Bb_ + rowB0 + slot1);                      \
    bf16x8 b11 = *(const bf16x8*)(Bb_ + rowB1 + slot1);                      \
    SBAR;                                                                    \
    __builtin_amdgcn_s_setprio(1);                                           \
    acc[0][0] = MFMA32(a00, b00, acc[0][0]);                                 \
    acc[0][1] = MFMA32(a00, b10, acc[0][1]);                                 \
    acc[1][0] = MFMA32(a10, b00, acc[1][0]);                                 \
    acc[1][1] = MFMA32(a10, b10, acc[1][1]);                                 \
    __builtin_amdgcn_s_setprio(0);                                           \
    SBAR;                                                                    \
    asm volatile("s_waitcnt lgkmcnt(0)" ::: "memory");                       \
    SBAR;                                                                    \
    BAR;                                                                     \
    STG;                                                                     \
    SBAR;                                                                    \
    __builtin_amdgcn_s_setprio(1);                                           \
    acc[0][0] = MFMA32(a01, b01, acc[0][0]);                                 \
    acc[0][1] = MFMA32(a01, b11, acc[0][1]);                                 \
    acc[1][0] = MFMA32(a11, b01, acc[1][0]);                                 \
    acc[1][1] = MFMA32(a11, b11, acc[1][1]);                                 \
    __builtin_amdgcn_s_setprio(0);                                           \
    SBAR;                                                                    \
  } while (0)

  // prologue: tiles 0,1,2 staged (9 loads in flight)
  STAGE(0, 0);
  STAGE(1, 1);
  STAGE(2, 2);

  // steady state (nt = 128 = 3*41 + 5): ring-3, vmcnt(6) leaves tiles
  // u+1,u+2 (6 loads) in flight; stage u+3 after mid-tile rendezvous.
  int u = 0;
  for (int it = 0; it < 41; ++it) {
    TILE(0, "6", STAGE(0, u + 3));
    TILE(1, "6", STAGE(1, u + 4));
    TILE(2, "6", STAGE(2, u + 5));
    u += 3;
  }
  // u = 123
  TILE(0, "6", STAGE(0, 126));   // tile 123
  TILE(1, "6", STAGE(1, 127));   // tile 124
  TILE(2, "6", );                // tile 125
  TILE(0, "3", );                // tile 126
  TILE(1, "0", );                // tile 127

#undef TILE
#undef STAGE

  // epilogue: C/D layout col = lane&31, row = (reg&3) + 8*(reg>>2) + 4*g
  #pragma unroll
  for (int fn = 0; fn < 2; ++fn) {
    long col = n0 + wc * 64 + fn * 32 + l31;
    float bv = bias[col];
    #pragma unroll
    for (int fm = 0; fm < 2; ++fm) {
      long rbase = m0 + wr * 64 + fm * 32 + 4 * g;
      #pragma unroll
      for (int r = 0; r < 16; ++r) {
        long row = rbase + (r & 3) + 8 * (r >> 2);
        out[row * (long)N + col] = acc[fm][fn][r] + bv;
      }
    }
  }
}

extern "C" void kernel_launch(void* const* d_in, const int* in_sizes, int n_in,
                              void* d_out, int out_size, void* d_ws, size_t ws_size,
                              hipStream_t stream) {
  const float* x    = (const float*)d_in[0];
  const float* W    = (const float*)d_in[1];
  const float* b    = (const float*)d_in[2];
  const float* A    = (const float*)d_in[3];
  const float* Bm   = (const float*)d_in[4];

  const long D_out = in_sizes[2];                 // 4096
  const long D_in  = (long)in_sizes[1] / D_out;   // 4096
  const long M     = (long)in_sizes[0] / D_in;    // 16384
  const int  R     = (int)((long)in_sizes[3] / D_in);  // 16
  const int  K = (int)D_in, N = (int)D_out;

  unsigned short* xb = (unsigned short*)d_ws;
  unsigned short* wt = xb + (size_t)M * K;

  cvt_bf16_kernel<<<2048, 256, 0, stream>>>(x, xb, M * (long)K);
  build_wt_kernel<<<(K >> 6) * (N >> 6), 256, 0, stream>>>(W, A, Bm, wt, K, N, R);

  int grid = (int)((M / BM) * ((long)N / BN));    // 128 * 16 = 2048
  gemm_kernel<<<grid, 512, 72 * 1024, stream>>>(
      xb, wt, b, (float*)d_out, (int)M, N, K);
}

// Round 10
// 778.496 us; speedup vs baseline: 2.4562x; 2.4562x over previous
//
#include <hip/hip_runtime.h>

#define SCALE_LORA 2.0f
// GEMM: 256x256 tile, BK=16, 8 waves (2M x 4N, wave 128x64), 32x32x16 MFMA,
// NBUF=4 ring (64 KiB), REGISTER-PIPELINED: iter t reads tile t+1's fragments
// while MFMAing tile t's (independent sets -> LDS pipe overlaps MFMA pipe).
#define BM 256
#define BN 256
#define BK 16

#define AS1 __attribute__((address_space(1)))
#define AS3 __attribute__((address_space(3)))

using bf16x8 = __attribute__((ext_vector_type(8))) __bf16;
using f32x4  = __attribute__((ext_vector_type(4))) float;
using f32x16 = __attribute__((ext_vector_type(16))) float;
using u16x8  = __attribute__((ext_vector_type(8))) unsigned short;

#define MFMA32(a, b, c) __builtin_amdgcn_mfma_f32_32x32x16_bf16((a), (b), (c), 0, 0, 0)

static __device__ __forceinline__ unsigned short f2bf_rne(float f) {
  unsigned int u = __builtin_bit_cast(unsigned int, f);
  u += 0x7FFFu + ((u >> 16) & 1u);   // round-to-nearest-even
  return (unsigned short)(u >> 16);
}

// ---------- kernel 1: x f32 -> bf16 (vectorized, grid-stride) ----------
__global__ void cvt_bf16_kernel(const float* __restrict__ x,
                                unsigned short* __restrict__ xb, long n) {
  long stride = (long)gridDim.x * blockDim.x;
  long nv = n >> 3;
  for (long i = (long)blockIdx.x * blockDim.x + threadIdx.x; i < nv; i += stride) {
    long base = i << 3;
    f32x4 a = *(const f32x4*)(x + base);
    f32x4 b = *(const f32x4*)(x + base + 4);
    u16x8 o;
    o[0] = f2bf_rne(a[0]); o[1] = f2bf_rne(a[1]);
    o[2] = f2bf_rne(a[2]); o[3] = f2bf_rne(a[3]);
    o[4] = f2bf_rne(b[0]); o[5] = f2bf_rne(b[1]);
    o[6] = f2bf_rne(b[2]); o[7] = f2bf_rne(b[3]);
    *(u16x8*)(xb + base) = o;
  }
}

// ---------- kernel 2: W_eff^T = (W + 2*A@B)^T as bf16, N x K ----------
__global__ void build_wt_kernel(const float* __restrict__ W,
                                const float* __restrict__ A,
                                const float* __restrict__ Bmat,
                                unsigned short* __restrict__ WT,
                                int K, int N, int R) {
  __shared__ float Bs[16][64];
  __shared__ unsigned short Tt[64][66];
  int ntn = N >> 6;
  int kt = blockIdx.x / ntn, nt = blockIdx.x - kt * ntn;
  int k0 = kt << 6, n0 = nt << 6;
  int t = threadIdx.x;
  int tx = t & 63, ty = t >> 6;

  for (int i = t; i < R * 64; i += 256)
    Bs[i >> 6][i & 63] = Bmat[(long)(i >> 6) * N + n0 + (i & 63)];
  __syncthreads();

  for (int it = 0; it < 16; ++it) {
    int kl = (it << 2) + ty;
    long kg = k0 + kl;
    float w = W[kg * N + n0 + tx];
    const float* Ar = A + kg * R;
    float s = 0.f;
    for (int r = 0; r < R; ++r) s += Ar[r] * Bs[r][tx];
    Tt[kl][tx] = f2bf_rne(w + SCALE_LORA * s);
  }
  __syncthreads();

  for (int it = 0; it < 16; ++it) {
    int nn = (it << 2) + ty;
    WT[(long)(n0 + nn) * K + k0 + tx] = Tt[tx][nn];
  }
}

// ---------- kernel 3: register-pipelined 256² GEMM ----------
// LDS layout per buf (8 KB, 256 rows x 16 k bf16 = 32 B rows): row r,
// granule g (8 elems) stored at byte (r>>2)*128 + 16*((((r&3)<<1)|g) ^
// ((r>>2)&1)). Conflict-free: per 16-lane phase, 8 slots x 2 lanes.
// Staging: linear gload_lds dest; source row/granule pre-permuted to match.
__global__ __launch_bounds__(512, 2) void gemm_kernel(
    const unsigned short* __restrict__ Xb,  // M x K bf16
    const unsigned short* __restrict__ WT,  // N x K bf16 (pre-transposed)
    const float* __restrict__ bias,         // N f32
    float* __restrict__ out,                // M x N f32
    int M, int N, int K)
{
  extern __shared__ unsigned short lds[];   // 64 KiB
  char* ldsc = (char*)lds;
  // A bufs: b*8192, b=0..3 ; B bufs: 32768 + b*8192

  // XCD chunk map (r2-r7 verified: fetch ~0.6 GB at this geometry)
  int nwg = gridDim.x;
  int bid = blockIdx.x;
  if ((nwg & 7) == 0) {
    int cpx = nwg >> 3;
    bid = (bid & 7) * cpx + (bid >> 3);
  }
  int ntn = N / BN;                 // 16
  int tm = bid / ntn;
  int tn = bid - tm * ntn;
  const long m0 = (long)tm * BM;
  const long n0 = (long)tn * BN;

  int tid  = threadIdx.x;
  int lane = tid & 63;
  int wave = tid >> 6;
  int wr = wave >> 2;        // 0..1 : 128-row half (M)
  int wc = wave & 3;         // 0..3 : 64-col quarter (N)
  int l31 = lane & 31;
  int g   = lane >> 5;       // 0..1 (k-granule: k = 8g..8g+7)

  f32x16 acc[4][2] = {};     // [fm][fn], 128 f32/lane (AGPR)

  // staging: thread t writes 16B unit #t; that unit holds row r_local,
  // granule gs where x = (t&7)^((t>>3)&1), r_local = 4*(t>>3)+(x>>1), gs=x&1.
  {
  }
  int x_ = (tid & 7) ^ ((tid >> 3) & 1);
  int r_local = 4 * (tid >> 3) + (x_ >> 1);
  int cg = 8 * (x_ & 1);
  const unsigned short* aSrc = Xb + (m0 + r_local) * (long)K + cg;
  const unsigned short* bSrc = WT + (n0 + r_local) * (long)K + cg;
  const int ldsByte = tid * 16;

  // fragment read offsets: row R = {wr*128|wc*64} + fm*32 + l31, granule g.
  // slot = (((R&3)<<1)|g) ^ ((R>>2)&1); R&3 = l31&3, (R>>2)&1 = (l31>>2)&1;
  // fm adds 8 lines = +1024 B, slot unchanged.
  const int sl = (((l31 & 3) << 1) | g) ^ ((l31 >> 2) & 1);
  const int offA0 = wr * 4096 + (l31 >> 2) * 128 + sl * 16;
  const int offB0 = wc * 2048 + (l31 >> 2) * 128 + sl * 16;

  // ---- register sets (named -> static allocation) ----
#define DECLSET(s) bf16x8 a0##s, a1##s, a2##s, a3##s, b0##s, b1##s
  DECLSET(0); DECLSET(1);

#define READSET(s, BUFC) do {                                                \
    const char* Ab_ = ldsc + (BUFC) * 8192 + offA0;                          \
    const char* Bb_ = ldsc + 32768 + (BUFC) * 8192 + offB0;                  \
    a0##s = *(const bf16x8*)(Ab_);                                           \
    a1##s = *(const bf16x8*)(Ab_ + 1024);                                    \
    a2##s = *(const bf16x8*)(Ab_ + 2048);                                    \
    a3##s = *(const bf16x8*)(Ab_ + 3072);                                    \
    b0##s = *(const bf16x8*)(Bb_);                                           \
    b1##s = *(const bf16x8*)(Bb_ + 1024);                                    \
  } while (0)

#define MFMASET(s) do {                                                      \
    acc[0][0] = MFMA32(a0##s, b0##s, acc[0][0]);                             \
    acc[0][1] = MFMA32(a0##s, b1##s, acc[0][1]);                             \
    acc[1][0] = MFMA32(a1##s, b0##s, acc[1][0]);                             \
    acc[1][1] = MFMA32(a1##s, b1##s, acc[1][1]);                             \
    acc[2][0] = MFMA32(a2##s, b0##s, acc[2][0]);                             \
    acc[2][1] = MFMA32(a2##s, b1##s, acc[2][1]);                             \
    acc[3][0] = MFMA32(a3##s, b0##s, acc[3][0]);                             \
    acc[3][1] = MFMA32(a3##s, b1##s, acc[3][1]);                             \
  } while (0)

#define STAGE(BUFC, KT) do {                                                 \
    __builtin_amdgcn_global_load_lds(                                        \
      (const AS1 void*)(aSrc + (long)(KT) * 16),                             \
      (AS3 void*)(ldsc + (BUFC) * 8192 + ldsByte), 16, 0, 0);                \
    __builtin_amdgcn_global_load_lds(                                        \
      (const AS1 void*)(bSrc + (long)(KT) * 16),                             \
      (AS3 void*)(ldsc + 32768 + (BUFC) * 8192 + ldsByte), 16, 0, 0);        \
  } while (0)

#define SBAR  __builtin_amdgcn_sched_barrier(0)
#define BAR   __builtin_amdgcn_s_barrier()

  // iter t: drain own R(t) (lgkm0, ~free: issued a full iter ago); certify
  // staging(t+1) (vmcnt); BAR = rendezvous for BOTH read-readiness and
  // write-safety (buf (t+3)&3 = (t-1)&3 was drained before the PREV BAR).
#define ITER(SETM, SETR, BUFR, VMSTR, STG) do {                              \
    asm volatile("s_waitcnt lgkmcnt(0)" ::: "memory");                       \
    asm volatile("s_waitcnt vmcnt(" VMSTR ")" ::: "memory");                 \
    BAR;                                                                     \
    SBAR;                                                                    \
    READSET(SETR, BUFR);                                                     \
    STG;                                                                     \
    MFMASET(SETM);                                                           \
  } while (0)

  // nt = K/BK = 256 tiles.
  // prologue: stage tiles 0,1,2 (6 loads); wait stage0 (vmcnt(4)); R(0)->set0
  STAGE(0, 0);
  STAGE(1, 1);
  STAGE(2, 2);
  asm volatile("s_waitcnt vmcnt(4)" ::: "memory");
  BAR;
  SBAR;
  READSET(0, 0);

  // main: 63 x 4 tiles (t = 0..251), compile-time buf indices
  for (int i = 0; i < 63; ++i) {
    int t4 = i * 4;
    ITER(0, 1, 1, "2", STAGE(3, t4 + 3));
    ITER(1, 0, 2, "2", STAGE(0, t4 + 4));
    ITER(0, 1, 3, "2", STAGE(1, t4 + 5));
    ITER(1, 0, 0, "2", STAGE(2, t4 + 6));
  }
  // tails: t = 252 (stage 255), 253, 254, 255
  ITER(0, 1, 1, "2", STAGE(3, 255));
  ITER(1, 0, 2, "2", );
  ITER(0, 1, 3, "0", );
  asm volatile("s_waitcnt lgkmcnt(0)" ::: "memory");
  SBAR;
  MFMASET(1);

#undef ITER
#undef STAGE
#undef MFMASET
#undef READSET
#undef DECLSET

  // epilogue: 32x32 C/D layout (r9-verified): col = lane&31,
  // row = (reg&3) + 8*(reg>>2) + 4*(lane>>5)
  #pragma unroll
  for (int fn = 0; fn < 2; ++fn) {
    long col = n0 + wc * 64 + fn * 32 + l31;
    float bv = bias[col];
    #pragma unroll
    for (int fm = 0; fm < 4; ++fm) {
      long rbase = m0 + wr * 128 + fm * 32 + 4 * g;
      #pragma unroll
      for (int r = 0; r < 16; ++r) {
        long row = rbase + (r & 3) + 8 * (r >> 2);
        out[row * (long)N + col] = acc[fm][fn][r] + bv;
      }
    }
  }
}

extern "C" void kernel_launch(void* const* d_in, const int* in_sizes, int n_in,
                              void* d_out, int out_size, void* d_ws, size_t ws_size,
                              hipStream_t stream) {
  const float* x    = (const float*)d_in[0];
  const float* W    = (const float*)d_in[1];
  const float* b    = (const float*)d_in[2];
  const float* A    = (const float*)d_in[3];
  const float* Bm   = (const float*)d_in[4];

  const long D_out = in_sizes[2];                 // 4096
  const long D_in  = (long)in_sizes[1] / D_out;   // 4096
  const long M     = (long)in_sizes[0] / D_in;    // 16384
  const int  R     = (int)((long)in_sizes[3] / D_in);  // 16
  const int  K = (int)D_in, N = (int)D_out;

  unsigned short* xb = (unsigned short*)d_ws;
  unsigned short* wt = xb + (size_t)M * K;

  cvt_bf16_kernel<<<2048, 256, 0, stream>>>(x, xb, M * (long)K);
  build_wt_kernel<<<(K >> 6) * (N >> 6), 256, 0, stream>>>(W, A, Bm, wt, K, N, R);

  int grid = (int)((M / BM) * ((long)N / BN));    // 64 * 16 = 1024
  gemm_kernel<<<grid, 512, 64 * 1024, stream>>>(
      xb, wt, b, (float*)d_out, (int)M, N, K);
}

// Round 13
// 660.064 us; speedup vs baseline: 2.8969x; 1.1794x over previous
//
#include <hip/hip_runtime.h>

#define SCALE_LORA 2.0f
// i8 GEMM: 256x256 tile, BK=128 i8 (128-B rows), 8 waves (2M x 4N),
// 32x32x32 i8 MFMA, NBUF=2 (128 KiB), r7 4-phase schedule.
// r13 fix: staging dst = base + tid*16 (global_load_lds writes wave-uniform
// base + lane*16 — per-lane dest scatter is IGNORED by HW; r11/12 violated).
#define BM 256
#define BN 256
#define BKI 128

#define AS1 __attribute__((address_space(1)))
#define AS3 __attribute__((address_space(3)))

using f32x4  = __attribute__((ext_vector_type(4))) float;
using i32x4  = __attribute__((ext_vector_type(4))) int;
using i32x16 = __attribute__((ext_vector_type(16))) int;
using int4v  = __attribute__((ext_vector_type(4))) int;

#define MFMAI8(a, b, c) __builtin_amdgcn_mfma_i32_32x32x32_i8((a), (b), (c), 0, 0, 0)

// ---------- kernel 1: per-row quantize x -> i8 ----------
__global__ void quant_x_kernel(const float* __restrict__ x,
                               signed char* __restrict__ xq,
                               float* __restrict__ sx, int K) {
  __shared__ float wmax[8];
  long row = blockIdx.x;
  const float* xr = x + row * (long)K;
  int t = threadIdx.x;
  float v[16];
  #pragma unroll
  for (int j = 0; j < 4; ++j)
    *(f32x4*)(v + 4 * j) = *(const f32x4*)(xr + 16 * t + 4 * j);
  float m = 0.f;
  #pragma unroll
  for (int j = 0; j < 16; ++j) m = fmaxf(m, fabsf(v[j]));
  #pragma unroll
  for (int off = 1; off < 64; off <<= 1)
    m = fmaxf(m, __shfl_xor(m, off));
  int wid = t >> 6;
  if ((t & 63) == 0) wmax[wid] = m;
  __syncthreads();
  float rm = fmaxf(fmaxf(wmax[0], wmax[1]), fmaxf(wmax[2], wmax[3]));
  rm = fmaxf(rm, 1e-20f);
  float inv = 127.0f / rm;
  int4v pk;
  #pragma unroll
  for (int w = 0; w < 4; ++w) {
    int b0 = (int)rintf(v[4*w+0] * inv);
    int b1 = (int)rintf(v[4*w+1] * inv);
    int b2 = (int)rintf(v[4*w+2] * inv);
    int b3 = (int)rintf(v[4*w+3] * inv);
    b0 = max(-127, min(127, b0)); b1 = max(-127, min(127, b1));
    b2 = max(-127, min(127, b2)); b3 = max(-127, min(127, b3));
    pk[w] = (b0 & 255) | ((b1 & 255) << 8) | ((b2 & 255) << 16) | (b3 << 24);
  }
  *(int4v*)(xq + row * (long)K + 16 * t) = pk;
  if (t == 0) sx[row] = rm * (1.0f / 127.0f);
}

// ---------- kernel 2: per-col max of |W_eff| via atomicMax ----------
__global__ void colmax_kernel(const float* __restrict__ W,
                              const float* __restrict__ A,
                              const float* __restrict__ Bmat,
                              unsigned int* __restrict__ cmax,
                              int K, int N, int R) {
  int cb = blockIdx.x & 15, kc = blockIdx.x >> 4;
  int n = cb * 256 + threadIdx.x;
  float br[16];
  for (int r = 0; r < R; ++r) br[r] = Bmat[(long)r * N + n];
  float m = 0.f;
  int k0 = kc * 256;
  for (int k = k0; k < k0 + 256; ++k) {
    float s = W[(long)k * N + n];
    const float* Ak = A + (long)k * R;
    for (int r = 0; r < R; ++r) s += SCALE_LORA * Ak[r] * br[r];
    m = fmaxf(m, fabsf(s));
  }
  atomicMax(cmax + n, __float_as_uint(m));
}

// ---------- kernel 3: W_eff^T as i8, N x K ----------
__global__ void build_wtq_kernel(const float* __restrict__ W,
                                 const float* __restrict__ A,
                                 const float* __restrict__ Bmat,
                                 const unsigned int* __restrict__ cmax,
                                 signed char* __restrict__ WTq,
                                 int K, int N, int R) {
  __shared__ float Bs[16][64];
  __shared__ signed char Tt[64][68];
  int ntn = N >> 6;
  int kt = blockIdx.x / ntn, nt = blockIdx.x - kt * ntn;
  int k0 = kt << 6, n0 = nt << 6;
  int t = threadIdx.x;
  int tx = t & 63, ty = t >> 6;

  for (int i = t; i < R * 64; i += 256)
    Bs[i >> 6][i & 63] = Bmat[(long)(i >> 6) * N + n0 + (i & 63)];
  __syncthreads();

  float invc = 127.0f / fmaxf(__uint_as_float(cmax[n0 + tx]), 1e-20f);
  for (int it = 0; it < 16; ++it) {
    int kl = (it << 2) + ty;
    long kg = k0 + kl;
    float w = W[kg * N + n0 + tx];
    const float* Ar = A + kg * R;
    float s = 0.f;
    for (int r = 0; r < R; ++r) s += Ar[r] * Bs[r][tx];
    int q = (int)rintf((w + SCALE_LORA * s) * invc);
    Tt[kl][tx] = (signed char)max(-127, min(127, q));
  }
  __syncthreads();

  for (int it = 0; it < 16; ++it) {
    int nn = (it << 2) + ty;
    WTq[(long)(n0 + nn) * K + k0 + tx] = Tt[tx][nn];
  }
}

// ---------- kernel 4: i8 4-phase GEMM (r7 geometry + r7 staging) ----------
// LDS: row r (128 B) slot s (16 B) holds logical granule s ^ (r&7).
// Staging thread t: row t>>3, slot t&7, src granule (t&7)^((t>>3)&7);
// dst = base + j*8192 + tid*16 -> lane-stride 16, wave-uniform base (HW-legal).
__global__ __launch_bounds__(512, 2) void gemm_kernel(
    const signed char* __restrict__ Xq,   // M x K i8
    const signed char* __restrict__ WTq,  // N x K i8 (pre-transposed)
    const float* __restrict__ bias,       // N f32
    const float* __restrict__ sx,         // M f32 (rowmax/127)
    const unsigned int* __restrict__ cmax,// N colmax bits
    float* __restrict__ out,              // M x N f32
    int M, int N, int K)
{
  extern __shared__ char ldsc[];   // 128 KiB
  // A: [0, 65536) = 2 bufs x 32768 B; B: [65536, 131072).

  int nwg = gridDim.x;
  int bid = blockIdx.x;
  if ((nwg & 7) == 0) {
    int cpx = nwg >> 3;
    bid = (bid & 7) * cpx + (bid >> 3);
  }
  int ntn = N / BN;
  int tm = bid / ntn;
  int tn = bid - tm * ntn;
  const long m0 = (long)tm * BM;
  const long n0 = (long)tn * BN;

  int tid  = threadIdx.x;
  int lane = tid & 63;
  int wave = tid >> 6;
  int wr = wave >> 2;        // 0..1 : 128-row half (M)
  int wc = wave & 3;         // 0..3 : 64-col quarter (N)
  int l31 = lane & 31;
  int g   = lane >> 5;       // k-granule half

  i32x16 acc[4][2] = {};     // [fm][fn]

  // staging (r7 geometry): thread t -> row t>>3, slot t&7,
  // source granule (t&7)^((t>>3)&7), 16 B
  int srcg = 16 * ((tid & 7) ^ ((tid >> 3) & 7));
  const signed char* aSrc = Xq + (m0 + (tid >> 3)) * (long)K + srcg;
  const signed char* bSrc = WTq + (n0 + (tid >> 3)) * (long)K + srcg;
  const int ldsByte = tid * 16;

  // fragment read offsets: row byte = l31*128 (+fm*4096); slot byte =
  // 16*((2*kst+g) ^ (l31&7))   [stored slot holds logical granule slot^(r&7)]
  const int sw7 = l31 & 7;
  const int so0 = 16 * ((0 + g) ^ sw7);
  const int so1 = 16 * ((2 + g) ^ sw7);
  const int so2 = 16 * ((4 + g) ^ sw7);
  const int so3 = 16 * ((6 + g) ^ sw7);
  const int rowA = wr * 16384 + l31 * 128;
  const int rowB = wc * 8192  + l31 * 128;

  const int nt = K / BKI;   // 32

#define STGA(b, h, kt) do {                                                  \
    _Pragma("unroll")                                                        \
    for (int j_ = 0; j_ < 2; ++j_)                                           \
      __builtin_amdgcn_global_load_lds(                                      \
        (const AS1 void*)(aSrc + ((h)*128 + j_*64)*(long)K + (long)(kt)*BKI),\
        (AS3 void*)(ldsc + (b)*32768 + (h)*16384 + j_*8192 + ldsByte),       \
        16, 0, 0);                                                           \
  } while (0)
#define STGB(b, h, kt) do {                                                  \
    _Pragma("unroll")                                                        \
    for (int j_ = 0; j_ < 2; ++j_)                                           \
      __builtin_amdgcn_global_load_lds(                                      \
        (const AS1 void*)(bSrc + ((h)*128 + j_*64)*(long)K + (long)(kt)*BKI),\
        (AS3 void*)(ldsc + 65536 + (b)*32768 + (h)*16384 + j_*8192 +         \
                    ldsByte), 16, 0, 0);                                     \
  } while (0)

#define SBAR  __builtin_amdgcn_sched_barrier(0)
#define BAR   __builtin_amdgcn_s_barrier()
#define LGKM0 do { asm volatile("s_waitcnt lgkmcnt(0)" ::: "memory"); SBAR; } while (0)
#define LGKM8 do { asm volatile("s_waitcnt lgkmcnt(8)" ::: "memory"); } while (0)

#define RD_A(arr, fmB) do {                                                  \
    _Pragma("unroll")                                                        \
    for (int fi_ = 0; fi_ < 2; ++fi_) {                                      \
      const char* p_ = Ab_ + ((fmB) + fi_) * 4096;                           \
      arr[fi_][0] = *(const i32x4*)(p_ + so0);                               \
      arr[fi_][1] = *(const i32x4*)(p_ + so1);                               \
      arr[fi_][2] = *(const i32x4*)(p_ + so2);                               \
      arr[fi_][3] = *(const i32x4*)(p_ + so3);                               \
    }                                                                        \
  } while (0)
#define RD_B(arr, fnB) do {                                                  \
    const char* p_ = Bb_ + (fnB) * 4096;                                     \
    arr[0] = *(const i32x4*)(p_ + so0);                                      \
    arr[1] = *(const i32x4*)(p_ + so1);                                      \
    arr[2] = *(const i32x4*)(p_ + so2);                                      \
    arr[3] = *(const i32x4*)(p_ + so3);                                      \
  } while (0)
#define QUAD(aarr, barr, fmB, fn) do {                                       \
    __builtin_amdgcn_s_setprio(1);                                           \
    _Pragma("unroll")                                                        \
    for (int fi_ = 0; fi_ < 2; ++fi_)                                        \
      _Pragma("unroll")                                                      \
      for (int ks_ = 0; ks_ < 4; ++ks_)                                      \
        acc[(fmB)+fi_][fn] = MFMAI8(aarr[fi_][ks_], barr[ks_],               \
                                    acc[(fmB)+fi_][fn]);                     \
    __builtin_amdgcn_s_setprio(0);                                           \
  } while (0)

  // 4 phases per K-tile (r7-faithful): top vmcnt(W1)+BAR rendezvous.
#define TILE4(B_, W1, S1, S2, S3, S4) do {                                   \
    asm volatile("s_waitcnt vmcnt(" W1 ")" ::: "memory");                    \
    BAR;                                                                     \
    const char* Ab_ = ldsc + (B_)*32768 + rowA;                              \
    const char* Bb_ = ldsc + 65536 + (B_)*32768 + rowB;                      \
    i32x4 af_[2][4], bl_[4], bh_[4], ag_[2][4];                              \
    /* ph1: 12 reads (A fm0-1, B fn0); stage; quad(fm0-1, fn0) */            \
    RD_A(af_, 0);                                                            \
    RD_B(bl_, 0);                                                            \
    S1;                                                                      \
    LGKM8;                                                                   \
    SBAR; BAR; LGKM0;                                                        \
    QUAD(af_, bl_, 0, 0);                                                    \
    SBAR; BAR;                                                               \
    /* ph2: 4 reads (B fn1); stage; quad(fm0-1, fn1) */                      \
    RD_B(bh_, 1);                                                            \
    S2;                                                                      \
    SBAR; BAR; LGKM0;                                                        \
    QUAD(af_, bh_, 0, 1);                                                    \
    SBAR; BAR;                                                               \
    /* ph3: 8 reads (A fm2-3); stage; quad(fm2-3, fn0) */                    \
    RD_A(ag_, 2);                                                            \
    S3;                                                                      \
    SBAR; BAR; LGKM0;                                                        \
    QUAD(ag_, bl_, 2, 0);                                                    \
    SBAR; BAR;                                                               \
    /* ph4: 0 reads; stage; quad(fm2-3, fn1); no closing BAR */              \
    S4;                                                                      \
    SBAR;                                                                    \
    QUAD(ag_, bh_, 2, 1);                                                    \
    SBAR;                                                                    \
  } while (0)

  // prologue: tile 0 all 4 halves + tile 1 halves B0,A0 (12 loads/wave)
  STGB(0, 0, 0); STGA(0, 0, 0); STGB(0, 1, 0); STGA(0, 1, 0);
  STGB(1, 0, 1); STGA(1, 0, 1);

  // steady: 12 outstanding at each tile top; vmcnt(4) drains exactly the
  // 8 loads of the buffer about to be read (r7-verified ledger).
  const int npair = nt / 2;
  for (int i = 0; i < npair - 1; ++i) {
    int t2 = 2 * i;
    TILE4(0, "4", STGB(1,1,t2+1), STGA(1,1,t2+1), STGB(0,0,t2+2), STGA(0,0,t2+2));
    TILE4(1, "4", STGB(0,1,t2+2), STGA(0,1,t2+2), STGB(1,0,t2+3), STGA(1,0,t2+3));
  }
  TILE4(0, "4", STGB(1,1,nt-1), STGA(1,1,nt-1), , );
  TILE4(1, "0", , , , );

#undef TILE4
#undef QUAD
#undef RD_A
#undef RD_B
#undef STGA
#undef STGB

  // epilogue: 32x32 C/D layout (verified): col = lane&31,
  // row = (reg&3) + 8*(reg>>2) + 4*(lane>>5). out = sx[row]*sw[col]*acc + b.
  #pragma unroll
  for (int fn = 0; fn < 2; ++fn) {
    long col = n0 + wc * 64 + fn * 32 + l31;
    float swc = __uint_as_float(cmax[col]) * (1.0f / 127.0f);
    float bv = bias[col];
    #pragma unroll
    for (int fm = 0; fm < 4; ++fm) {
      long rbase = m0 + wr * 128 + fm * 32 + 4 * g;
      #pragma unroll
      for (int r = 0; r < 16; ++r) {
        long row = rbase + (r & 3) + 8 * (r >> 2);
        out[row * (long)N + col] = (float)acc[fm][fn][r] * sx[row] * swc + bv;
      }
    }
  }
}

extern "C" void kernel_launch(void* const* d_in, const int* in_sizes, int n_in,
                              void* d_out, int out_size, void* d_ws, size_t ws_size,
                              hipStream_t stream) {
  const float* x    = (const float*)d_in[0];
  const float* W    = (const float*)d_in[1];
  const float* b    = (const float*)d_in[2];
  const float* A    = (const float*)d_in[3];
  const float* Bm   = (const float*)d_in[4];

  const long D_out = in_sizes[2];                 // 4096
  const long D_in  = (long)in_sizes[1] / D_out;   // 4096
  const long M     = (long)in_sizes[0] / D_in;    // 16384
  const int  R     = (int)((long)in_sizes[3] / D_in);  // 16
  const int  K = (int)D_in, N = (int)D_out;

  // ws layout (bytes): Xq [0, M*K); WTq [M*K, M*K+N*K); sx (M f32);
  // cmax (N u32)
  char* wsc = (char*)d_ws;
  signed char* xq  = (signed char*)wsc;
  signed char* wtq = (signed char*)(wsc + (size_t)M * K);
  float* sx = (float*)(wsc + (size_t)M * K + (size_t)N * K);
  unsigned int* cmaxU = (unsigned int*)(wsc + (size_t)M * K + (size_t)N * K
                                        + (size_t)M * 4);

  hipMemsetAsync(cmaxU, 0, (size_t)N * 4, stream);
  quant_x_kernel<<<(int)M, 256, 0, stream>>>(x, xq, sx, K);
  colmax_kernel<<<256, 256, 0, stream>>>(W, A, Bm, cmaxU, K, N, R);
  build_wtq_kernel<<<(K >> 6) * (N >> 6), 256, 0, stream>>>(
      W, A, Bm, cmaxU, wtq, K, N, R);

  int grid = (int)((M / BM) * ((long)N / BN));    // 64 * 16 = 1024
  gemm_kernel<<<grid, 512, 128 * 1024, stream>>>(
      xq, wtq, b, sx, cmaxU, (float*)d_out, (int)M, N, K);
}

// Round 14
// 445.728 us; speedup vs baseline: 4.2899x; 1.4809x over previous
//
#include <hip/hip_runtime.h>

#define SCALE_LORA 2.0f
// i8 GEMM: 256x256 tile, BK=128 i8, 8 waves, 32x32x32 i8 MFMA, NBUF=2,
// r7 4-phase schedule (r13-passing). r14: lean preprocessing —
// coalesced quant_x; bf16 build_wt (r7-proven) + one-pass quantize_wt.
#define BM 256
#define BN 256
#define BKI 128

#define AS1 __attribute__((address_space(1)))
#define AS3 __attribute__((address_space(3)))

using f32x4  = __attribute__((ext_vector_type(4))) float;
using i32x4  = __attribute__((ext_vector_type(4))) int;
using i32x16 = __attribute__((ext_vector_type(16))) int;
using u16x8  = __attribute__((ext_vector_type(8))) unsigned short;

#define MFMAI8(a, b, c) __builtin_amdgcn_mfma_i32_32x32x32_i8((a), (b), (c), 0, 0, 0)

static __device__ __forceinline__ unsigned short f2bf_rne(float f) {
  unsigned int u = __builtin_bit_cast(unsigned int, f);
  u += 0x7FFFu + ((u >> 16) & 1u);
  return (unsigned short)(u >> 16);
}
static __device__ __forceinline__ float bf2f(unsigned short b) {
  unsigned int u = (unsigned int)b << 16;
  return __builtin_bit_cast(float, u);
}

// ---------- kernel 1: per-row quantize x -> i8 (fully coalesced) ----------
// block 256 thr = 1 row. thread t, chunk j: elems 4t + 1024j.
__global__ void quant_x_kernel(const float* __restrict__ x,
                               signed char* __restrict__ xq,
                               float* __restrict__ sx, int K) {
  __shared__ float wmax[4];
  long row = blockIdx.x;
  const float* xr = x + row * (long)K;
  int t = threadIdx.x;
  f32x4 v[4];
  #pragma unroll
  for (int j = 0; j < 4; ++j)
    v[j] = *(const f32x4*)(xr + 4 * t + 1024 * j);
  float m = 0.f;
  #pragma unroll
  for (int j = 0; j < 4; ++j)
    #pragma unroll
    for (int e = 0; e < 4; ++e) m = fmaxf(m, fabsf(v[j][e]));
  #pragma unroll
  for (int off = 1; off < 64; off <<= 1)
    m = fmaxf(m, __shfl_xor(m, off));
  if ((t & 63) == 0) wmax[t >> 6] = m;
  __syncthreads();
  float rm = fmaxf(fmaxf(wmax[0], wmax[1]), fmaxf(wmax[2], wmax[3]));
  rm = fmaxf(rm, 1e-20f);
  float inv = 127.0f / rm;
  #pragma unroll
  for (int j = 0; j < 4; ++j) {
    int b0 = max(-127, min(127, (int)rintf(v[j][0] * inv)));
    int b1 = max(-127, min(127, (int)rintf(v[j][1] * inv)));
    int b2 = max(-127, min(127, (int)rintf(v[j][2] * inv)));
    int b3 = max(-127, min(127, (int)rintf(v[j][3] * inv)));
    unsigned int pk = (b0 & 255) | ((b1 & 255) << 8) | ((b2 & 255) << 16)
                      | ((unsigned)b3 << 24);
    *(unsigned int*)(xq + row * (long)K + 4 * t + 1024 * j) = pk;
  }
  if (t == 0) sx[row] = rm * (1.0f / 127.0f);
}

// ---------- kernel 2: W_eff^T = (W + 2*A@B)^T as bf16 (r7-proven) ----------
__global__ void build_wt_kernel(const float* __restrict__ W,
                                const float* __restrict__ A,
                                const float* __restrict__ Bmat,
                                unsigned short* __restrict__ WT,
                                int K, int N, int R) {
  __shared__ float Bs[16][64];
  __shared__ unsigned short Tt[64][66];
  int ntn = N >> 6;
  int kt = blockIdx.x / ntn, nt = blockIdx.x - kt * ntn;
  int k0 = kt << 6, n0 = nt << 6;
  int t = threadIdx.x;
  int tx = t & 63, ty = t >> 6;

  for (int i = t; i < R * 64; i += 256)
    Bs[i >> 6][i & 63] = Bmat[(long)(i >> 6) * N + n0 + (i & 63)];
  __syncthreads();

  for (int it = 0; it < 16; ++it) {
    int kl = (it << 2) + ty;
    long kg = k0 + kl;
    float w = W[kg * N + n0 + tx];
    const float* Ar = A + kg * R;
    float s = 0.f;
    for (int r = 0; r < R; ++r) s += Ar[r] * Bs[r][tx];
    Tt[kl][tx] = f2bf_rne(w + SCALE_LORA * s);
  }
  __syncthreads();

  for (int it = 0; it < 16; ++it) {
    int nn = (it << 2) + ty;
    WT[(long)(n0 + nn) * K + k0 + tx] = Tt[tx][nn];
  }
}

// ---------- kernel 3: WT bf16 -> colmax + i8 quantize (one pass) ----------
// block 256 thr = 1 row of WT (= 1 col of W_eff), 4096 bf16 = 8 KB.
// thread t: elems 8t and 8t+2048 (16-B loads, coalesced).
__global__ void quantize_wt_kernel(const unsigned short* __restrict__ WT,
                                   signed char* __restrict__ WTq,
                                   float* __restrict__ sw, int K) {
  __shared__ float wmax[4];
  long n = blockIdx.x;
  const unsigned short* wr = WT + n * (long)K;
  int t = threadIdx.x;
  u16x8 u0 = *(const u16x8*)(wr + 8 * t);
  u16x8 u1 = *(const u16x8*)(wr + 8 * t + 2048);
  float f0[8], f1[8];
  float m = 0.f;
  #pragma unroll
  for (int e = 0; e < 8; ++e) {
    f0[e] = bf2f(u0[e]); f1[e] = bf2f(u1[e]);
    m = fmaxf(m, fmaxf(fabsf(f0[e]), fabsf(f1[e])));
  }
  #pragma unroll
  for (int off = 1; off < 64; off <<= 1)
    m = fmaxf(m, __shfl_xor(m, off));
  if ((t & 63) == 0) wmax[t >> 6] = m;
  __syncthreads();
  float rm = fmaxf(fmaxf(wmax[0], wmax[1]), fmaxf(wmax[2], wmax[3]));
  rm = fmaxf(rm, 1e-20f);
  float inv = 127.0f / rm;
  unsigned long long p0 = 0, p1 = 0;
  #pragma unroll
  for (int e = 0; e < 8; ++e) {
    int q0 = max(-127, min(127, (int)rintf(f0[e] * inv)));
    int q1 = max(-127, min(127, (int)rintf(f1[e] * inv)));
    p0 |= (unsigned long long)(q0 & 255) << (8 * e);
    p1 |= (unsigned long long)(q1 & 255) << (8 * e);
  }
  *(unsigned long long*)(WTq + n * (long)K + 8 * t) = p0;
  *(unsigned long long*)(WTq + n * (long)K + 8 * t + 2048) = p1;
  if (t == 0) sw[n] = rm * (1.0f / 127.0f);
}

// ---------- kernel 4: i8 4-phase GEMM (r13-passing, byte-identical core) ----
__global__ __launch_bounds__(512, 2) void gemm_kernel(
    const signed char* __restrict__ Xq,   // M x K i8
    const signed char* __restrict__ WTq,  // N x K i8 (pre-transposed)
    const float* __restrict__ bias,       // N f32
    const float* __restrict__ sx,         // M f32
    const float* __restrict__ sw,         // N f32
    float* __restrict__ out,              // M x N f32
    int M, int N, int K)
{
  extern __shared__ char ldsc[];   // 128 KiB

  int nwg = gridDim.x;
  int bid = blockIdx.x;
  if ((nwg & 7) == 0) {
    int cpx = nwg >> 3;
    bid = (bid & 7) * cpx + (bid >> 3);
  }
  int ntn = N / BN;
  int tm = bid / ntn;
  int tn = bid - tm * ntn;
  const long m0 = (long)tm * BM;
  const long n0 = (long)tn * BN;

  int tid  = threadIdx.x;
  int lane = tid & 63;
  int wave = tid >> 6;
  int wr = wave >> 2;
  int wc = wave & 3;
  int l31 = lane & 31;
  int g   = lane >> 5;

  i32x16 acc[4][2] = {};

  int srcg = 16 * ((tid & 7) ^ ((tid >> 3) & 7));
  const signed char* aSrc = Xq + (m0 + (tid >> 3)) * (long)K + srcg;
  const signed char* bSrc = WTq + (n0 + (tid >> 3)) * (long)K + srcg;
  const int ldsByte = tid * 16;

  const int sw7 = l31 & 7;
  const int so0 = 16 * ((0 + g) ^ sw7);
  const int so1 = 16 * ((2 + g) ^ sw7);
  const int so2 = 16 * ((4 + g) ^ sw7);
  const int so3 = 16 * ((6 + g) ^ sw7);
  const int rowA = wr * 16384 + l31 * 128;
  const int rowB = wc * 8192  + l31 * 128;

  const int nt = K / BKI;   // 32

#define STGA(b, h, kt) do {                                                  \
    _Pragma("unroll")                                                        \
    for (int j_ = 0; j_ < 2; ++j_)                                           \
      __builtin_amdgcn_global_load_lds(                                      \
        (const AS1 void*)(aSrc + ((h)*128 + j_*64)*(long)K + (long)(kt)*BKI),\
        (AS3 void*)(ldsc + (b)*32768 + (h)*16384 + j_*8192 + ldsByte),       \
        16, 0, 0);                                                           \
  } while (0)
#define STGB(b, h, kt) do {                                                  \
    _Pragma("unroll")                                                        \
    for (int j_ = 0; j_ < 2; ++j_)                                           \
      __builtin_amdgcn_global_load_lds(                                      \
        (const AS1 void*)(bSrc + ((h)*128 + j_*64)*(long)K + (long)(kt)*BKI),\
        (AS3 void*)(ldsc + 65536 + (b)*32768 + (h)*16384 + j_*8192 +         \
                    ldsByte), 16, 0, 0);                                     \
  } while (0)

#define SBAR  __builtin_amdgcn_sched_barrier(0)
#define BAR   __builtin_amdgcn_s_barrier()
#define LGKM0 do { asm volatile("s_waitcnt lgkmcnt(0)" ::: "memory"); SBAR; } while (0)
#define LGKM8 do { asm volatile("s_waitcnt lgkmcnt(8)" ::: "memory"); } while (0)

#define RD_A(arr, fmB) do {                                                  \
    _Pragma("unroll")                                                        \
    for (int fi_ = 0; fi_ < 2; ++fi_) {                                      \
      const char* p_ = Ab_ + ((fmB) + fi_) * 4096;                           \
      arr[fi_][0] = *(const i32x4*)(p_ + so0);                               \
      arr[fi_][1] = *(const i32x4*)(p_ + so1);                               \
      arr[fi_][2] = *(const i32x4*)(p_ + so2);                               \
      arr[fi_][3] = *(const i32x4*)(p_ + so3);                               \
    }                                                                        \
  } while (0)
#define RD_B(arr, fnB) do {                                                  \
    const char* p_ = Bb_ + (fnB) * 4096;                                     \
    arr[0] = *(const i32x4*)(p_ + so0);                                      \
    arr[1] = *(const i32x4*)(p_ + so1);                                      \
    arr[2] = *(const i32x4*)(p_ + so2);                                      \
    arr[3] = *(const i32x4*)(p_ + so3);                                      \
  } while (0)
#define QUAD(aarr, barr, fmB, fn) do {                                       \
    __builtin_amdgcn_s_setprio(1);                                           \
    _Pragma("unroll")                                                        \
    for (int fi_ = 0; fi_ < 2; ++fi_)                                        \
      _Pragma("unroll")                                                      \
      for (int ks_ = 0; ks_ < 4; ++ks_)                                      \
        acc[(fmB)+fi_][fn] = MFMAI8(aarr[fi_][ks_], barr[ks_],               \
                                    acc[(fmB)+fi_][fn]);                     \
    __builtin_amdgcn_s_setprio(0);                                           \
  } while (0)

#define TILE4(B_, W1, S1, S2, S3, S4) do {                                   \
    asm volatile("s_waitcnt vmcnt(" W1 ")" ::: "memory");                    \
    BAR;                                                                     \
    const char* Ab_ = ldsc + (B_)*32768 + rowA;                              \
    const char* Bb_ = ldsc + 65536 + (B_)*32768 + rowB;                      \
    i32x4 af_[2][4], bl_[4], bh_[4], ag_[2][4];                              \
    RD_A(af_, 0);                                                            \
    RD_B(bl_, 0);                                                            \
    S1;                                                                      \
    LGKM8;                                                                   \
    SBAR; BAR; LGKM0;                                                        \
    QUAD(af_, bl_, 0, 0);                                                    \
    SBAR; BAR;                                                               \
    RD_B(bh_, 1);                                                            \
    S2;                                                                      \
    SBAR; BAR; LGKM0;                                                        \
    QUAD(af_, bh_, 0, 1);                                                    \
    SBAR; BAR;                                                               \
    RD_A(ag_, 2);                                                            \
    S3;                                                                      \
    SBAR; BAR; LGKM0;                                                        \
    QUAD(ag_, bl_, 2, 0);                                                    \
    SBAR; BAR;                                                               \
    S4;                                                                      \
    SBAR;                                                                    \
    QUAD(ag_, bh_, 2, 1);                                                    \
    SBAR;                                                                    \
  } while (0)

  STGB(0, 0, 0); STGA(0, 0, 0); STGB(0, 1, 0); STGA(0, 1, 0);
  STGB(1, 0, 1); STGA(1, 0, 1);

  const int npair = nt / 2;
  for (int i = 0; i < npair - 1; ++i) {
    int t2 = 2 * i;
    TILE4(0, "4", STGB(1,1,t2+1), STGA(1,1,t2+1), STGB(0,0,t2+2), STGA(0,0,t2+2));
    TILE4(1, "4", STGB(0,1,t2+2), STGA(0,1,t2+2), STGB(1,0,t2+3), STGA(1,0,t2+3));
  }
  TILE4(0, "4", STGB(1,1,nt-1), STGA(1,1,nt-1), , );
  TILE4(1, "0", , , , );

#undef TILE4
#undef QUAD
#undef RD_A
#undef RD_B
#undef STGA
#undef STGB

  // epilogue: 32x32 C/D layout: col = lane&31, row = (reg&3)+8*(reg>>2)+4*g
  #pragma unroll
  for (int fn = 0; fn < 2; ++fn) {
    long col = n0 + wc * 64 + fn * 32 + l31;
    float swc = sw[col];
    float bv = bias[col];
    #pragma unroll
    for (int fm = 0; fm < 4; ++fm) {
      long rbase = m0 + wr * 128 + fm * 32 + 4 * g;
      #pragma unroll
      for (int r = 0; r < 16; ++r) {
        long row = rbase + (r & 3) + 8 * (r >> 2);
        out[row * (long)N + col] = (float)acc[fm][fn][r] * sx[row] * swc + bv;
      }
    }
  }
}

extern "C" void kernel_launch(void* const* d_in, const int* in_sizes, int n_in,
                              void* d_out, int out_size, void* d_ws, size_t ws_size,
                              hipStream_t stream) {
  const float* x    = (const float*)d_in[0];
  const float* W    = (const float*)d_in[1];
  const float* b    = (const float*)d_in[2];
  const float* A    = (const float*)d_in[3];
  const float* Bm   = (const float*)d_in[4];

  const long D_out = in_sizes[2];                 // 4096
  const long D_in  = (long)in_sizes[1] / D_out;   // 4096
  const long M     = (long)in_sizes[0] / D_in;    // 16384
  const int  R     = (int)((long)in_sizes[3] / D_in);  // 16
  const int  K = (int)D_in, N = (int)D_out;

  // ws layout (bytes): xq (M*K i8); wt bf16 (N*K*2); wtq (N*K i8);
  // sx (M f32); sw (N f32)  — ~117.6 MB total
  char* wsc = (char*)d_ws;
  signed char*    xq  = (signed char*)wsc;
  unsigned short* wt  = (unsigned short*)(wsc + (size_t)M * K);
  signed char*    wtq = (signed char*)(wsc + (size_t)M * K + (size_t)N * K * 2);
  float* sx = (float*)(wsc + (size_t)M * K + (size_t)N * K * 3);
  float* sw = (float*)(wsc + (size_t)M * K + (size_t)N * K * 3 + (size_t)M * 4);

  quant_x_kernel<<<(int)M, 256, 0, stream>>>(x, xq, sx, K);
  build_wt_kernel<<<(K >> 6) * (N >> 6), 256, 0, stream>>>(W, A, Bm, wt, K, N, R);
  quantize_wt_kernel<<<N, 256, 0, stream>>>(wt, wtq, sw, K);

  int grid = (int)((M / BM) * ((long)N / BN));    // 64 * 16 = 1024
  gemm_kernel<<<grid, 512, 128 * 1024, stream>>>(
      xq, wtq, b, sx, sw, (float*)d_out, (int)M, N, K);
}